// Round 1
// baseline (230.669 us; speedup 1.0000x reference)
//
#include <hip/hip_runtime.h>
#include <math.h>

#define EMB 768
#define NB 2
#define NWIN 512                 // windows per batch (8*8*8)
#define NROWS (NB*NWIN)          // 1024 total query rows
#define SWIN 64                  // window size 4*4*4
#define HRDIM 32
#define ROWF (NROWS*EMB)         // floats per [1024][768] buffer

// ---------------------------------------------------------------------------
// Generic tiled fp32 GEMM: C[M][N] = A[M][K] * op(B) (+ bias)
//   TRANSB=true : out[m][n] = sum_k A[m][k] * B[n][k]   (B is [N][K])
//   TRANSB=false: out[m][n] = sum_k A[m][k] * B[k][n]   (B is [K][N])
// 64x64 tile, BK=32, 256 threads, 4x4 micro-tile per thread.
// Requires M%64==0, N%64==0, K%32==0.
// ---------------------------------------------------------------------------
template<bool TRANSB, bool BIAS>
__global__ __launch_bounds__(256)
void gemm_f32(const float* __restrict__ A, const float* __restrict__ B,
              const float* __restrict__ bias, float* __restrict__ C,
              int M, int N, int K) {
  const int BM = 64, BN = 64, BK = 32;
  __shared__ float As[BK][BM];
  __shared__ float Bs[BK][BN];
  const int t  = threadIdx.x;
  const int m0 = blockIdx.y * BM;
  const int n0 = blockIdx.x * BN;
  const int tm = t >> 4;          // 0..15
  const int tn = t & 15;          // 0..15
  float acc[4][4] = {};

  for (int k0 = 0; k0 < K; k0 += BK) {
    // ---- load A tile (64 rows x 32 k) as 512 float4, transpose into As[k][m]
#pragma unroll
    for (int r = 0; r < 2; ++r) {
      int idx = t + r * 256;
      int row = idx >> 3;         // 0..63
      int kq  = idx & 7;          // 0..7  (float4 index along k)
      float4 v = *(const float4*)&A[(size_t)(m0 + row) * K + k0 + kq * 4];
      As[kq * 4 + 0][row] = v.x;
      As[kq * 4 + 1][row] = v.y;
      As[kq * 4 + 2][row] = v.z;
      As[kq * 4 + 3][row] = v.w;
    }
    // ---- load B tile
    if (TRANSB) {
#pragma unroll
      for (int r = 0; r < 2; ++r) {
        int idx = t + r * 256;
        int col = idx >> 3;       // output col within tile
        int kq  = idx & 7;
        float4 v = *(const float4*)&B[(size_t)(n0 + col) * K + k0 + kq * 4];
        Bs[kq * 4 + 0][col] = v.x;
        Bs[kq * 4 + 1][col] = v.y;
        Bs[kq * 4 + 2][col] = v.z;
        Bs[kq * 4 + 3][col] = v.w;
      }
    } else {
#pragma unroll
      for (int r = 0; r < 2; ++r) {
        int idx = t + r * 256;
        int kk = idx >> 4;        // 0..31
        int cq = idx & 15;        // 0..15 (float4 index along n)
        float4 v = *(const float4*)&B[(size_t)(k0 + kk) * N + n0 + cq * 4];
        *(float4*)&Bs[kk][cq * 4] = v;
      }
    }
    __syncthreads();

#pragma unroll
    for (int kk = 0; kk < BK; ++kk) {
      float4 av = *(const float4*)&As[kk][tm * 4];
      float4 bv = *(const float4*)&Bs[kk][tn * 4];
      float a[4] = {av.x, av.y, av.z, av.w};
      float b[4] = {bv.x, bv.y, bv.z, bv.w};
#pragma unroll
      for (int i = 0; i < 4; ++i)
#pragma unroll
        for (int j = 0; j < 4; ++j)
          acc[i][j] = fmaf(a[i], b[j], acc[i][j]);
    }
    __syncthreads();
  }

#pragma unroll
  for (int i = 0; i < 4; ++i) {
    int m = m0 + tm * 4 + i;
#pragma unroll
    for (int j = 0; j < 4; ++j) {
      int n = n0 + tn * 4 + j;
      float v = acc[i][j];
      if (BIAS) v += bias[n];
      C[(size_t)m * N + n] = v;
    }
  }
}

// ---------------------------------------------------------------------------
// Attention core. One block per (batch, window).
// scores_s = scale * (qtilde . hr_s)   (the q.bk constant is softmax-invariant)
// z = softmax(scores) @ HR_window      (bias/Wv applied later as a GEMM)
// HR read from HBM once (pass 2 re-reads the 196 KB window out of L2).
// ---------------------------------------------------------------------------
__global__ __launch_bounds__(256)
void attn_kernel(const float* __restrict__ HR, const float* __restrict__ qt,
                 float* __restrict__ z) {
  const int g = blockIdx.x;       // 0..1023
  const int b = g >> 9;
  const int n = g & 511;
  const int db = n >> 6, wb = (n >> 3) & 7, hb = n & 7;

  __shared__ float qs[EMB];
  __shared__ float sc[SWIN];
  __shared__ int   vb[SWIN];      // per-s voxel base offset in floats (fits int32)

  const int t = threadIdx.x;
  const int wave = t >> 6, lane = t & 63;

  // stage qtilde row (768 f32 = 192 float4)
  if (t < 192)
    *(float4*)&qs[t * 4] = *(const float4*)&qt[(size_t)g * EMB + t * 4];
  if (t < SWIN) {
    int sd = t >> 4, sw = (t >> 2) & 3, sh = t & 3;
    int D = db * 4 + sd, W = wb * 4 + sw, H = hb * 4 + sh;
    vb[t] = (((b * HRDIM + D) * HRDIM + W) * HRDIM + H) * EMB;
  }
  __syncthreads();

  // ---- pass 1: 64 dot products, wave w owns s = w*16 .. w*16+15
  for (int si = 0; si < 16; ++si) {
    int s = wave * 16 + si;
    const float* row = HR + vb[s];
    float p = 0.f;
#pragma unroll
    for (int r = 0; r < 3; ++r) {
      int c = (lane + r * 64) * 4;
      float4 hv = *(const float4*)&row[c];
      float4 qv = *(const float4*)&qs[c];
      p = fmaf(hv.x, qv.x, p);
      p = fmaf(hv.y, qv.y, p);
      p = fmaf(hv.z, qv.z, p);
      p = fmaf(hv.w, qv.w, p);
    }
#pragma unroll
    for (int o = 32; o > 0; o >>= 1) p += __shfl_xor(p, o, 64);
    if (lane == 0) sc[s] = p;
  }
  __syncthreads();

  // ---- softmax over 64 scores (wave 0)
  if (wave == 0) {
    const float scale = 0.036084391824351615f; // 1/sqrt(768)
    float v = sc[lane] * scale;
    float mx = v;
#pragma unroll
    for (int o = 32; o > 0; o >>= 1) mx = fmaxf(mx, __shfl_xor(mx, o, 64));
    float e = expf(v - mx);
    float sum = e;
#pragma unroll
    for (int o = 32; o > 0; o >>= 1) sum += __shfl_xor(sum, o, 64);
    sc[lane] = e / sum;
  }
  __syncthreads();

  // ---- pass 2: z[c] = sum_s attn[s] * HR[s][c]  (window is L2-resident now)
  if (t < 192) {
    float4 acc = {0.f, 0.f, 0.f, 0.f};
#pragma unroll 8
    for (int s = 0; s < SWIN; ++s) {
      float a = sc[s];
      float4 hv = *(const float4*)&HR[(size_t)vb[s] + t * 4];
      acc.x = fmaf(a, hv.x, acc.x);
      acc.y = fmaf(a, hv.y, acc.y);
      acc.z = fmaf(a, hv.z, acc.z);
      acc.w = fmaf(a, hv.w, acc.w);
    }
    *(float4*)&z[(size_t)g * EMB + t * 4] = acc;
  }
}

// ---------------------------------------------------------------------------
// res = Q + X ; out = LayerNorm(res) * g + b.  One block per row.
// ---------------------------------------------------------------------------
__global__ __launch_bounds__(256)
void resid_ln_kernel(const float* __restrict__ Q, const float* __restrict__ X,
                     const float* __restrict__ gma, const float* __restrict__ bta,
                     float* __restrict__ out) {
  const int row = blockIdx.x;
  const int t = threadIdx.x;
  const int wave = t >> 6, lane = t & 63;
  __shared__ float red[4];

  float v[3];
  float s = 0.f;
#pragma unroll
  for (int r = 0; r < 3; ++r) {
    int c = t + r * 256;
    v[r] = Q[(size_t)row * EMB + c] + X[(size_t)row * EMB + c];
    s += v[r];
  }
#pragma unroll
  for (int o = 32; o > 0; o >>= 1) s += __shfl_xor(s, o, 64);
  if (lane == 0) red[wave] = s;
  __syncthreads();
  float mu = (red[0] + red[1] + red[2] + red[3]) * (1.f / EMB);
  __syncthreads();

  float q = 0.f;
#pragma unroll
  for (int r = 0; r < 3; ++r) {
    float d = v[r] - mu;
    q += d * d;
  }
#pragma unroll
  for (int o = 32; o > 0; o >>= 1) q += __shfl_xor(q, o, 64);
  if (lane == 0) red[wave] = q;
  __syncthreads();
  float var = (red[0] + red[1] + red[2] + red[3]) * (1.f / EMB);
  float inv = rsqrtf(var + 1e-5f);

#pragma unroll
  for (int r = 0; r < 3; ++r) {
    int c = t + r * 256;
    out[(size_t)row * EMB + c] = (v[r] - mu) * inv * gma[c] + bta[c];
  }
}

// ---------------------------------------------------------------------------
extern "C" void kernel_launch(void* const* d_in, const int* in_sizes, int n_in,
                              void* d_out, int out_size, void* d_ws, size_t ws_size,
                              hipStream_t stream) {
  const float* LR  = (const float*)d_in[0];
  const float* HR  = (const float*)d_in[1];
  const float* Wq  = (const float*)d_in[2];
  const float* bq  = (const float*)d_in[3];
  const float* Wk  = (const float*)d_in[4];
  // d_in[5] = Wk_b: constant shift inside softmax -> provably no effect
  const float* Wv  = (const float*)d_in[6];
  const float* bv  = (const float*)d_in[7];
  const float* Wo  = (const float*)d_in[8];
  const float* bo  = (const float*)d_in[9];
  const float* lng = (const float*)d_in[10];
  const float* lnb = (const float*)d_in[11];
  float* out = (float*)d_out;

  float* ws = (float*)d_ws;
  float* Q  = ws + 0 * (size_t)ROWF;   // projected queries          [1024][768]
  float* qt = ws + 1 * (size_t)ROWF;   // qtilde = Q @ Wk            [1024][768]
  float* z  = ws + 2 * (size_t)ROWF;   // attn @ HR                  [1024][768]
  float* y  = ws + 3 * (size_t)ROWF;   // z @ Wv^T + bv              [1024][768]
  float* x  = ws + 4 * (size_t)ROWF;   // y @ Wo^T + bo              [1024][768]

  dim3 blk(256);
  dim3 gg(EMB / 64, NROWS / 64);       // (12, 16) = 192 blocks

  // Q = LR @ Wq^T + bq
  gemm_f32<true, true><<<gg, blk, 0, stream>>>(LR, Wq, bq, Q, NROWS, EMB, EMB);
  // qt = Q @ Wk      (K-projection folded into the query side)
  gemm_f32<false, false><<<gg, blk, 0, stream>>>(Q, Wk, nullptr, qt, NROWS, EMB, EMB);
  // z = softmax(scale * qt . HR) @ HR
  attn_kernel<<<dim3(NROWS), blk, 0, stream>>>(HR, qt, z);
  // y = z @ Wv^T + bv   (V-projection moved after the attention average)
  gemm_f32<true, true><<<gg, blk, 0, stream>>>(z, Wv, bv, y, NROWS, EMB, EMB);
  // x = y @ Wo^T + bo
  gemm_f32<true, true><<<gg, blk, 0, stream>>>(y, Wo, bo, x, NROWS, EMB, EMB);
  // out = LN(Q + x) * g + b
  resid_ln_kernel<<<dim3(NROWS), blk, 0, stream>>>(Q, x, lng, lnb, out);
}

// Round 2
// 124.701 us; speedup vs baseline: 1.8498x; 1.8498x over previous
//
#include <hip/hip_runtime.h>
#include <hip/hip_bf16.h>
#include <math.h>

#define EMB 768
#define NB 2
#define NWIN 512
#define NROWS (NB*NWIN)          // 1024
#define SWIN 64
#define HRDIM 32
#define ROWF (NROWS*EMB)         // 786432 elems in a [1024][768] buffer
#define WELEM (EMB*EMB)          // 589824

using bfrag = __attribute__((ext_vector_type(8))) short;   // 8 bf16 (4 VGPRs)
using f32x4 = __attribute__((ext_vector_type(4))) float;

#define GL16(g, l)  __builtin_amdgcn_global_load_lds(                         \
    (const __attribute__((address_space(1))) void*)(g),                       \
    (__attribute__((address_space(3))) void*)(l), 16, 0, 0)

// ---------------------------------------------------------------------------
// fp32 -> bf16 elementwise convert (8 elems/thread)
// ---------------------------------------------------------------------------
__global__ __launch_bounds__(256)
void f2b_kernel(const float* __restrict__ in, __hip_bfloat16* __restrict__ out,
                int n8) {
  int i = blockIdx.x * 256 + threadIdx.x;
  if (i >= n8) return;
  float4 a = *(const float4*)&in[(size_t)i * 8];
  float4 b = *(const float4*)&in[(size_t)i * 8 + 4];
  __hip_bfloat16 t[8];
  t[0] = __float2bfloat16(a.x); t[1] = __float2bfloat16(a.y);
  t[2] = __float2bfloat16(a.z); t[3] = __float2bfloat16(a.w);
  t[4] = __float2bfloat16(b.x); t[5] = __float2bfloat16(b.y);
  t[6] = __float2bfloat16(b.z); t[7] = __float2bfloat16(b.w);
  *(uint4*)&out[(size_t)i * 8] = *(const uint4*)t;
}

// ---------------------------------------------------------------------------
// fp32 [768][768] -> bf16 transposed [768][768]: out[n][k] = in[k][n]
// ---------------------------------------------------------------------------
__global__ __launch_bounds__(256)
void f2bT_kernel(const float* __restrict__ in, __hip_bfloat16* __restrict__ out) {
  __shared__ float tile[32][33];
  const int bi = blockIdx.x, bj = blockIdx.y;
  const int c = threadIdx.x & 31, r8 = threadIdx.x >> 5;
#pragma unroll
  for (int rr = 0; rr < 4; ++rr) {
    int r = r8 + rr * 8;
    tile[c][r] = in[(size_t)(bi * 32 + r) * EMB + bj * 32 + c];
  }
  __syncthreads();
#pragma unroll
  for (int rr = 0; rr < 4; ++rr) {
    int n = r8 + rr * 8;
    out[(size_t)(bj * 32 + n) * EMB + bi * 32 + c] = __float2bfloat16(tile[n][c]);
  }
}

// ---------------------------------------------------------------------------
// MFMA bf16 GEMM: C[m][n] = sum_k A[m][k] * Bm[n][k]  (+ bias[n])
// A [M][K] bf16, Bm [N][K] bf16. 64x64 tile, BK=64, 4 waves, double-buffered
// LDS staged by global_load_lds(16B) with XOR chunk swizzle applied on the
// (per-lane) global source so LDS dest stays linear; frag reads use the same
// swizzle -> 2-way bank aliasing only (free).
// ---------------------------------------------------------------------------
template<bool BIAS, bool WF32, bool WB16>
__global__ __launch_bounds__(256)
void gemm_bf16(const __hip_bfloat16* __restrict__ A,
               const __hip_bfloat16* __restrict__ Bm,
               const float* __restrict__ bias,
               float* __restrict__ Cf, __hip_bfloat16* __restrict__ Cb,
               int M, int N, int K) {
  __shared__ short lsA[2][64 * 64];   // 8 KB per buffer, swizzled chunks
  __shared__ short lsB[2][64 * 64];
  const int t = threadIdx.x;
  const int w = t >> 6, lane = t & 63;
  const int lr = lane & 15, lk = lane >> 4;          // frag row / k-group
  const int m0 = blockIdx.y * 64, n0 = blockIdx.x * 64;

  // staging: thread t owns 16B chunks t and t+256 of each 512-chunk tile.
  // chunk p -> LDS row p>>3, slot p&7; logical k-chunk = slot ^ (row&7).
  const int r0 = t >> 3, c0 = t & 7;
  const int kc = c0 ^ (r0 & 7);                      // same for row r0+32 (32%8==0)
  const __hip_bfloat16* aptr0 = A + (size_t)(m0 + r0) * K + kc * 8;
  const __hip_bfloat16* aptr1 = A + (size_t)(m0 + r0 + 32) * K + kc * 8;
  const __hip_bfloat16* bptr0 = Bm + (size_t)(n0 + r0) * K + kc * 8;
  const __hip_bfloat16* bptr1 = Bm + (size_t)(n0 + r0 + 32) * K + kc * 8;
  const int wbase = w * 512;                         // shorts; lanes fill +lane*8

  // fragment read offsets (shorts), swizzled
  const int arow = w * 16 + lr;
  int aoff[2], boff[4][2];
#pragma unroll
  for (int ks = 0; ks < 2; ++ks)
    aoff[ks] = arow * 64 + (((ks << 2) | lk) ^ (arow & 7)) * 8;
#pragma unroll
  for (int f = 0; f < 4; ++f) {
    int br = f * 16 + lr;
#pragma unroll
    for (int ks = 0; ks < 2; ++ks)
      boff[f][ks] = br * 64 + (((ks << 2) | lk) ^ (br & 7)) * 8;
  }

  f32x4 acc[4];
#pragma unroll
  for (int f = 0; f < 4; ++f) acc[f] = (f32x4){0.f, 0.f, 0.f, 0.f};

  const int NT = K / 64;
  // prologue
  GL16(aptr0, &lsA[0][wbase]);
  GL16(aptr1, &lsA[0][wbase + 2048]);
  GL16(bptr0, &lsB[0][wbase]);
  GL16(bptr1, &lsB[0][wbase + 2048]);
  __syncthreads();

  int buf = 0;
  for (int kt = 0; kt < NT; ++kt) {
    if (kt + 1 < NT) {
      int ko = (kt + 1) * 64;
      GL16(aptr0 + ko, &lsA[buf ^ 1][wbase]);
      GL16(aptr1 + ko, &lsA[buf ^ 1][wbase + 2048]);
      GL16(bptr0 + ko, &lsB[buf ^ 1][wbase]);
      GL16(bptr1 + ko, &lsB[buf ^ 1][wbase + 2048]);
    }
    bfrag a0 = *(const bfrag*)&lsA[buf][aoff[0]];
    bfrag a1 = *(const bfrag*)&lsA[buf][aoff[1]];
    bfrag b00 = *(const bfrag*)&lsB[buf][boff[0][0]];
    bfrag b01 = *(const bfrag*)&lsB[buf][boff[0][1]];
    bfrag b10 = *(const bfrag*)&lsB[buf][boff[1][0]];
    bfrag b11 = *(const bfrag*)&lsB[buf][boff[1][1]];
    bfrag b20 = *(const bfrag*)&lsB[buf][boff[2][0]];
    bfrag b21 = *(const bfrag*)&lsB[buf][boff[2][1]];
    bfrag b30 = *(const bfrag*)&lsB[buf][boff[3][0]];
    bfrag b31 = *(const bfrag*)&lsB[buf][boff[3][1]];
    acc[0] = __builtin_amdgcn_mfma_f32_16x16x32_bf16(a0, b00, acc[0], 0, 0, 0);
    acc[0] = __builtin_amdgcn_mfma_f32_16x16x32_bf16(a1, b01, acc[0], 0, 0, 0);
    acc[1] = __builtin_amdgcn_mfma_f32_16x16x32_bf16(a0, b10, acc[1], 0, 0, 0);
    acc[1] = __builtin_amdgcn_mfma_f32_16x16x32_bf16(a1, b11, acc[1], 0, 0, 0);
    acc[2] = __builtin_amdgcn_mfma_f32_16x16x32_bf16(a0, b20, acc[2], 0, 0, 0);
    acc[2] = __builtin_amdgcn_mfma_f32_16x16x32_bf16(a1, b21, acc[2], 0, 0, 0);
    acc[3] = __builtin_amdgcn_mfma_f32_16x16x32_bf16(a0, b30, acc[3], 0, 0, 0);
    acc[3] = __builtin_amdgcn_mfma_f32_16x16x32_bf16(a1, b31, acc[3], 0, 0, 0);
    __syncthreads();       // drains vmcnt (stage visible) + protects buffers
    buf ^= 1;
  }

  float bs[4] = {0.f, 0.f, 0.f, 0.f};
  if (BIAS) {
#pragma unroll
    for (int f = 0; f < 4; ++f) bs[f] = bias[n0 + f * 16 + lr];
  }
#pragma unroll
  for (int f = 0; f < 4; ++f) {
    int n = n0 + f * 16 + lr;                        // C col = lane&15
#pragma unroll
    for (int j = 0; j < 4; ++j) {
      int m = m0 + w * 16 + lk * 4 + j;              // C row = (lane>>4)*4+reg
      float v = acc[f][j] + bs[f];
      if (WF32) Cf[(size_t)m * N + n] = v;
      if (WB16) Cb[(size_t)m * N + n] = __float2bfloat16(v);
    }
  }
}

// ---------------------------------------------------------------------------
// Attention core (fp32, HBM-bound on HR). z written as bf16 for the next GEMM.
// ---------------------------------------------------------------------------
__global__ __launch_bounds__(256)
void attn_kernel(const float* __restrict__ HR, const float* __restrict__ qt,
                 __hip_bfloat16* __restrict__ zb) {
  const int g = blockIdx.x;
  const int b = g >> 9;
  const int n = g & 511;
  const int db = n >> 6, wb = (n >> 3) & 7, hb = n & 7;

  __shared__ float qs[EMB];
  __shared__ float sc[SWIN];
  __shared__ int   vb[SWIN];

  const int t = threadIdx.x;
  const int wave = t >> 6, lane = t & 63;

  if (t < 192)
    *(float4*)&qs[t * 4] = *(const float4*)&qt[(size_t)g * EMB + t * 4];
  if (t < SWIN) {
    int sd = t >> 4, sw = (t >> 2) & 3, sh = t & 3;
    int D = db * 4 + sd, W = wb * 4 + sw, H = hb * 4 + sh;
    vb[t] = (((b * HRDIM + D) * HRDIM + W) * HRDIM + H) * EMB;
  }
  __syncthreads();

  for (int si = 0; si < 16; ++si) {
    int s = wave * 16 + si;
    const float* row = HR + vb[s];
    float p = 0.f;
#pragma unroll
    for (int r = 0; r < 3; ++r) {
      int c = (lane + r * 64) * 4;
      float4 hv = *(const float4*)&row[c];
      float4 qv = *(const float4*)&qs[c];
      p = fmaf(hv.x, qv.x, p);
      p = fmaf(hv.y, qv.y, p);
      p = fmaf(hv.z, qv.z, p);
      p = fmaf(hv.w, qv.w, p);
    }
#pragma unroll
    for (int o = 32; o > 0; o >>= 1) p += __shfl_xor(p, o, 64);
    if (lane == 0) sc[s] = p;
  }
  __syncthreads();

  if (wave == 0) {
    const float scale = 0.036084391824351615f; // 1/sqrt(768)
    float v = sc[lane] * scale;
    float mx = v;
#pragma unroll
    for (int o = 32; o > 0; o >>= 1) mx = fmaxf(mx, __shfl_xor(mx, o, 64));
    float e = expf(v - mx);
    float sum = e;
#pragma unroll
    for (int o = 32; o > 0; o >>= 1) sum += __shfl_xor(sum, o, 64);
    sc[lane] = e / sum;
  }
  __syncthreads();

  if (t < 192) {
    float4 acc = {0.f, 0.f, 0.f, 0.f};
#pragma unroll 8
    for (int s = 0; s < SWIN; ++s) {
      float a = sc[s];
      float4 hv = *(const float4*)&HR[(size_t)vb[s] + t * 4];
      acc.x = fmaf(a, hv.x, acc.x);
      acc.y = fmaf(a, hv.y, acc.y);
      acc.z = fmaf(a, hv.z, acc.z);
      acc.w = fmaf(a, hv.w, acc.w);
    }
    __hip_bfloat16 o[4];
    o[0] = __float2bfloat16(acc.x); o[1] = __float2bfloat16(acc.y);
    o[2] = __float2bfloat16(acc.z); o[3] = __float2bfloat16(acc.w);
    *(uint2*)&zb[(size_t)g * EMB + t * 4] = *(const uint2*)o;
  }
}

// ---------------------------------------------------------------------------
// res = Q + X ; out = LayerNorm(res) * g + b
// ---------------------------------------------------------------------------
__global__ __launch_bounds__(256)
void resid_ln_kernel(const float* __restrict__ Q, const float* __restrict__ X,
                     const float* __restrict__ gma, const float* __restrict__ bta,
                     float* __restrict__ out) {
  const int row = blockIdx.x;
  const int t = threadIdx.x;
  const int wave = t >> 6, lane = t & 63;
  __shared__ float red[4];

  float v[3];
  float s = 0.f;
#pragma unroll
  for (int r = 0; r < 3; ++r) {
    int c = t + r * 256;
    v[r] = Q[(size_t)row * EMB + c] + X[(size_t)row * EMB + c];
    s += v[r];
  }
#pragma unroll
  for (int o = 32; o > 0; o >>= 1) s += __shfl_xor(s, o, 64);
  if (lane == 0) red[wave] = s;
  __syncthreads();
  float mu = (red[0] + red[1] + red[2] + red[3]) * (1.f / EMB);
  __syncthreads();

  float q = 0.f;
#pragma unroll
  for (int r = 0; r < 3; ++r) {
    float d = v[r] - mu;
    q += d * d;
  }
#pragma unroll
  for (int o = 32; o > 0; o >>= 1) q += __shfl_xor(q, o, 64);
  if (lane == 0) red[wave] = q;
  __syncthreads();
  float var = (red[0] + red[1] + red[2] + red[3]) * (1.f / EMB);
  float inv = rsqrtf(var + 1e-5f);

#pragma unroll
  for (int r = 0; r < 3; ++r) {
    int c = t + r * 256;
    out[(size_t)row * EMB + c] = (v[r] - mu) * inv * gma[c] + bta[c];
  }
}

// ---------------------------------------------------------------------------
extern "C" void kernel_launch(void* const* d_in, const int* in_sizes, int n_in,
                              void* d_out, int out_size, void* d_ws, size_t ws_size,
                              hipStream_t stream) {
  const float* LR  = (const float*)d_in[0];
  const float* HR  = (const float*)d_in[1];
  const float* Wq  = (const float*)d_in[2];
  const float* bq  = (const float*)d_in[3];
  const float* Wk  = (const float*)d_in[4];
  // d_in[5] = Wk_b: softmax-invariant constant -> dropped (exact)
  const float* Wv  = (const float*)d_in[6];
  const float* bv  = (const float*)d_in[7];
  const float* Wo  = (const float*)d_in[8];
  const float* bo  = (const float*)d_in[9];
  const float* lng = (const float*)d_in[10];
  const float* lnb = (const float*)d_in[11];
  float* out = (float*)d_out;

  char* ws = (char*)d_ws;
  float* Qf = (float*)(ws + 0);                       // [1024][768] f32
  float* qt = (float*)(ws + 3145728);                 // [1024][768] f32
  float* x  = (float*)(ws + 6291456);                 // [1024][768] f32
  __hip_bfloat16* LRb  = (__hip_bfloat16*)(ws + 9437184);
  __hip_bfloat16* Qb   = (__hip_bfloat16*)(ws + 11010048);
  __hip_bfloat16* zb   = (__hip_bfloat16*)(ws + 12582912);
  __hip_bfloat16* yb   = (__hip_bfloat16*)(ws + 14155776);
  __hip_bfloat16* Wqb  = (__hip_bfloat16*)(ws + 15728640);
  __hip_bfloat16* WkTb = (__hip_bfloat16*)(ws + 16908288);
  __hip_bfloat16* Wvb  = (__hip_bfloat16*)(ws + 18087936);
  __hip_bfloat16* Wob  = (__hip_bfloat16*)(ws + 19267584);

  dim3 blk(256);
  dim3 gg(EMB / 64, NROWS / 64);                      // (12,16)

  // converts
  f2b_kernel<<<dim3(ROWF / 8 / 256), blk, 0, stream>>>(LR, LRb, ROWF / 8);
  f2b_kernel<<<dim3(WELEM / 8 / 256), blk, 0, stream>>>(Wq, Wqb, WELEM / 8);
  f2bT_kernel<<<dim3(24, 24), blk, 0, stream>>>(Wk, WkTb);
  f2b_kernel<<<dim3(WELEM / 8 / 256), blk, 0, stream>>>(Wv, Wvb, WELEM / 8);
  f2b_kernel<<<dim3(WELEM / 8 / 256), blk, 0, stream>>>(Wo, Wob, WELEM / 8);

  // Q = LR @ Wq^T + bq        (f32 for residual, bf16 for next GEMM)
  gemm_bf16<true, true, true><<<gg, blk, 0, stream>>>(
      LRb, Wqb, bq, Qf, Qb, NROWS, EMB, EMB);
  // qt = Q @ Wk               (Wk^T pre-transposed; f32 out for attn)
  gemm_bf16<false, true, false><<<gg, blk, 0, stream>>>(
      Qb, WkTb, nullptr, qt, nullptr, NROWS, EMB, EMB);
  // z = softmax(scale * qt . HR) @ HR   (bf16 out)
  attn_kernel<<<dim3(NROWS), blk, 0, stream>>>(HR, qt, zb);
  // y = z @ Wv^T + bv         (bf16 out)
  gemm_bf16<true, false, true><<<gg, blk, 0, stream>>>(
      zb, Wvb, bv, nullptr, yb, NROWS, EMB, EMB);
  // x = y @ Wo^T + bo         (f32 out)
  gemm_bf16<true, true, false><<<gg, blk, 0, stream>>>(
      yb, Wob, bo, x, nullptr, NROWS, EMB, EMB);
  // out = LN(Q + x) * g + b
  resid_ln_kernel<<<dim3(NROWS), blk, 0, stream>>>(Qf, x, lng, lnb, out);
}

// Round 3
// 102.156 us; speedup vs baseline: 2.2580x; 1.2207x over previous
//
#include <hip/hip_runtime.h>
#include <hip/hip_bf16.h>
#include <math.h>

#define EMB 768
#define NB 2
#define NWIN 512
#define NROWS (NB*NWIN)          // 1024
#define SWIN 64
#define HRDIM 32
#define ROWF (NROWS*EMB)         // 786432 elems in a [1024][768] buffer
#define WELEM (EMB*EMB)          // 589824

using bfrag = __attribute__((ext_vector_type(8))) short;   // 8 bf16 (4 VGPRs)
using f32x4 = __attribute__((ext_vector_type(4))) float;

#define GL16(g, l)  __builtin_amdgcn_global_load_lds(                         \
    (const __attribute__((address_space(1))) void*)(g),                       \
    (__attribute__((address_space(3))) void*)(l), 16, 0, 0)

// ---------------------------------------------------------------------------
// fp32 -> bf16 elementwise convert (8 elems/thread)
// ---------------------------------------------------------------------------
__global__ __launch_bounds__(256)
void f2b_kernel(const float* __restrict__ in, __hip_bfloat16* __restrict__ out,
                int n8) {
  int i = blockIdx.x * 256 + threadIdx.x;
  if (i >= n8) return;
  float4 a = *(const float4*)&in[(size_t)i * 8];
  float4 b = *(const float4*)&in[(size_t)i * 8 + 4];
  __hip_bfloat16 t[8];
  t[0] = __float2bfloat16(a.x); t[1] = __float2bfloat16(a.y);
  t[2] = __float2bfloat16(a.z); t[3] = __float2bfloat16(a.w);
  t[4] = __float2bfloat16(b.x); t[5] = __float2bfloat16(b.y);
  t[6] = __float2bfloat16(b.z); t[7] = __float2bfloat16(b.w);
  *(uint4*)&out[(size_t)i * 8] = *(const uint4*)t;
}

// batched variant: 3 weight matrices in one launch (blockIdx.y selects)
__global__ __launch_bounds__(256)
void f2b3_kernel(const float* __restrict__ inA, __hip_bfloat16* __restrict__ outA,
                 const float* __restrict__ inB, __hip_bfloat16* __restrict__ outB,
                 const float* __restrict__ inC, __hip_bfloat16* __restrict__ outC) {
  const float* in = (blockIdx.y == 0) ? inA : (blockIdx.y == 1) ? inB : inC;
  __hip_bfloat16* out = (blockIdx.y == 0) ? outA : (blockIdx.y == 1) ? outB : outC;
  int i = blockIdx.x * 256 + threadIdx.x;
  float4 a = *(const float4*)&in[(size_t)i * 8];
  float4 b = *(const float4*)&in[(size_t)i * 8 + 4];
  __hip_bfloat16 t[8];
  t[0] = __float2bfloat16(a.x); t[1] = __float2bfloat16(a.y);
  t[2] = __float2bfloat16(a.z); t[3] = __float2bfloat16(a.w);
  t[4] = __float2bfloat16(b.x); t[5] = __float2bfloat16(b.y);
  t[6] = __float2bfloat16(b.z); t[7] = __float2bfloat16(b.w);
  *(uint4*)&out[(size_t)i * 8] = *(const uint4*)t;
}

// ---------------------------------------------------------------------------
// fp32 [768][768] -> bf16 transposed: out[n][k] = in[k][n]
// ---------------------------------------------------------------------------
__global__ __launch_bounds__(256)
void f2bT_kernel(const float* __restrict__ in, __hip_bfloat16* __restrict__ out) {
  __shared__ float tile[32][33];
  const int bi = blockIdx.x, bj = blockIdx.y;
  const int c = threadIdx.x & 31, r8 = threadIdx.x >> 5;
#pragma unroll
  for (int rr = 0; rr < 4; ++rr) {
    int r = r8 + rr * 8;
    tile[c][r] = in[(size_t)(bi * 32 + r) * EMB + bj * 32 + c];
  }
  __syncthreads();
#pragma unroll
  for (int rr = 0; rr < 4; ++rr) {
    int n = r8 + rr * 8;
    out[(size_t)(bj * 32 + n) * EMB + bi * 32 + c] = __float2bfloat16(tile[n][c]);
  }
}

// ---------------------------------------------------------------------------
// MFMA bf16 GEMM: C[m][n] = sum_k A[m][k] * Bm[n][k]  (+ bias[n])
// 64x64 tile, BK=64, 4 waves, double-buffered global_load_lds(16B), XOR
// chunk swizzle via pre-swizzled global source (linear LDS dest).
// ---------------------------------------------------------------------------
template<bool BIAS, bool WF32, bool WB16>
__global__ __launch_bounds__(256)
void gemm_bf16(const __hip_bfloat16* __restrict__ A,
               const __hip_bfloat16* __restrict__ Bm,
               const float* __restrict__ bias,
               float* __restrict__ Cf, __hip_bfloat16* __restrict__ Cb,
               int M, int N, int K) {
  __shared__ short lsA[2][64 * 64];
  __shared__ short lsB[2][64 * 64];
  const int t = threadIdx.x;
  const int w = t >> 6, lane = t & 63;
  const int lr = lane & 15, lk = lane >> 4;
  const int m0 = blockIdx.y * 64, n0 = blockIdx.x * 64;

  const int r0 = t >> 3, c0 = t & 7;
  const int kc = c0 ^ (r0 & 7);
  const __hip_bfloat16* aptr0 = A + (size_t)(m0 + r0) * K + kc * 8;
  const __hip_bfloat16* aptr1 = A + (size_t)(m0 + r0 + 32) * K + kc * 8;
  const __hip_bfloat16* bptr0 = Bm + (size_t)(n0 + r0) * K + kc * 8;
  const __hip_bfloat16* bptr1 = Bm + (size_t)(n0 + r0 + 32) * K + kc * 8;
  const int wbase = w * 512;

  const int arow = w * 16 + lr;
  int aoff[2], boff[4][2];
#pragma unroll
  for (int ks = 0; ks < 2; ++ks)
    aoff[ks] = arow * 64 + (((ks << 2) | lk) ^ (arow & 7)) * 8;
#pragma unroll
  for (int f = 0; f < 4; ++f) {
    int br = f * 16 + lr;
#pragma unroll
    for (int ks = 0; ks < 2; ++ks)
      boff[f][ks] = br * 64 + (((ks << 2) | lk) ^ (br & 7)) * 8;
  }

  f32x4 acc[4];
#pragma unroll
  for (int f = 0; f < 4; ++f) acc[f] = (f32x4){0.f, 0.f, 0.f, 0.f};

  const int NT = K / 64;
  GL16(aptr0, &lsA[0][wbase]);
  GL16(aptr1, &lsA[0][wbase + 2048]);
  GL16(bptr0, &lsB[0][wbase]);
  GL16(bptr1, &lsB[0][wbase + 2048]);
  __syncthreads();

  int buf = 0;
  for (int kt = 0; kt < NT; ++kt) {
    if (kt + 1 < NT) {
      int ko = (kt + 1) * 64;
      GL16(aptr0 + ko, &lsA[buf ^ 1][wbase]);
      GL16(aptr1 + ko, &lsA[buf ^ 1][wbase + 2048]);
      GL16(bptr0 + ko, &lsB[buf ^ 1][wbase]);
      GL16(bptr1 + ko, &lsB[buf ^ 1][wbase + 2048]);
    }
    bfrag a0 = *(const bfrag*)&lsA[buf][aoff[0]];
    bfrag a1 = *(const bfrag*)&lsA[buf][aoff[1]];
    bfrag b00 = *(const bfrag*)&lsB[buf][boff[0][0]];
    bfrag b01 = *(const bfrag*)&lsB[buf][boff[0][1]];
    bfrag b10 = *(const bfrag*)&lsB[buf][boff[1][0]];
    bfrag b11 = *(const bfrag*)&lsB[buf][boff[1][1]];
    bfrag b20 = *(const bfrag*)&lsB[buf][boff[2][0]];
    bfrag b21 = *(const bfrag*)&lsB[buf][boff[2][1]];
    bfrag b30 = *(const bfrag*)&lsB[buf][boff[3][0]];
    bfrag b31 = *(const bfrag*)&lsB[buf][boff[3][1]];
    acc[0] = __builtin_amdgcn_mfma_f32_16x16x32_bf16(a0, b00, acc[0], 0, 0, 0);
    acc[0] = __builtin_amdgcn_mfma_f32_16x16x32_bf16(a1, b01, acc[0], 0, 0, 0);
    acc[1] = __builtin_amdgcn_mfma_f32_16x16x32_bf16(a0, b10, acc[1], 0, 0, 0);
    acc[1] = __builtin_amdgcn_mfma_f32_16x16x32_bf16(a1, b11, acc[1], 0, 0, 0);
    acc[2] = __builtin_amdgcn_mfma_f32_16x16x32_bf16(a0, b20, acc[2], 0, 0, 0);
    acc[2] = __builtin_amdgcn_mfma_f32_16x16x32_bf16(a1, b21, acc[2], 0, 0, 0);
    acc[3] = __builtin_amdgcn_mfma_f32_16x16x32_bf16(a0, b30, acc[3], 0, 0, 0);
    acc[3] = __builtin_amdgcn_mfma_f32_16x16x32_bf16(a1, b31, acc[3], 0, 0, 0);
    __syncthreads();
    buf ^= 1;
  }

  float bs[4] = {0.f, 0.f, 0.f, 0.f};
  if (BIAS) {
#pragma unroll
    for (int f = 0; f < 4; ++f) bs[f] = bias[n0 + f * 16 + lr];
  }
#pragma unroll
  for (int f = 0; f < 4; ++f) {
    int n = n0 + f * 16 + lr;
#pragma unroll
    for (int j = 0; j < 4; ++j) {
      int m = m0 + w * 16 + lk * 4 + j;
      float v = acc[f][j] + bs[f];
      if (WF32) Cf[(size_t)m * N + n] = v;
      if (WB16) Cb[(size_t)m * N + n] = __float2bfloat16(v);
    }
  }
}

// ---------------------------------------------------------------------------
// Attention core, single HBM pass over HR.
// Pass 1: fp32 scores (full precision) + convert window to bf16 into LDS.
// Pass 2: weighted sum out of LDS. 512 threads, ~100 KB LDS -> 1 block/CU.
// ---------------------------------------------------------------------------
__global__ __launch_bounds__(512)
void attn_kernel(const float* __restrict__ HR, const float* __restrict__ qt,
                 __hip_bfloat16* __restrict__ zb) {
  const int g = blockIdx.x;
  const int b = g >> 9;
  const int n = g & 511;
  const int db = n >> 6, wb = (n >> 3) & 7, hb = n & 7;

  __shared__ float qs[EMB];
  __shared__ float sc[SWIN];
  __shared__ int   vb[SWIN];
  __shared__ short win[SWIN][EMB];   // 96 KB bf16 window cache

  const int t = threadIdx.x;
  const int w = t >> 6, lane = t & 63;

  if (t < 192)
    *(float4*)&qs[t * 4] = *(const float4*)&qt[(size_t)g * EMB + t * 4];
  if (t < SWIN) {
    int sd = t >> 4, sw = (t >> 2) & 3, sh = t & 3;
    int D = db * 4 + sd, W = wb * 4 + sw, H = hb * 4 + sh;
    vb[t] = (((b * HRDIM + D) * HRDIM + W) * HRDIM + H) * EMB;
  }
  __syncthreads();

  // ---- pass 1: wave w owns rows s = w*8 .. w*8+7. Issue all 24 float4
  // loads up-front (HBM MLP), then dot + bf16-stage + reduce.
  float4 qv[3];
#pragma unroll
  for (int r = 0; r < 3; ++r)
    qv[r] = *(const float4*)&qs[(lane + r * 64) * 4];

  float4 hv[8][3];
#pragma unroll
  for (int i = 0; i < 8; ++i) {
    const float* row = HR + vb[w * 8 + i];
#pragma unroll
    for (int r = 0; r < 3; ++r)
      hv[i][r] = *(const float4*)&row[(lane + r * 64) * 4];
  }

  float p[8];
#pragma unroll
  for (int i = 0; i < 8; ++i) {
    float acc = 0.f;
#pragma unroll
    for (int r = 0; r < 3; ++r) {
      acc = fmaf(hv[i][r].x, qv[r].x, acc);
      acc = fmaf(hv[i][r].y, qv[r].y, acc);
      acc = fmaf(hv[i][r].z, qv[r].z, acc);
      acc = fmaf(hv[i][r].w, qv[r].w, acc);
      __hip_bfloat16 o[4];
      o[0] = __float2bfloat16(hv[i][r].x);
      o[1] = __float2bfloat16(hv[i][r].y);
      o[2] = __float2bfloat16(hv[i][r].z);
      o[3] = __float2bfloat16(hv[i][r].w);
      *(uint2*)&win[w * 8 + i][(lane + r * 64) * 4] = *(const uint2*)o;
    }
    p[i] = acc;
  }
#pragma unroll
  for (int i = 0; i < 8; ++i) {
#pragma unroll
    for (int o = 32; o > 0; o >>= 1) p[i] += __shfl_xor(p[i], o, 64);
    if (lane == 0) sc[w * 8 + i] = p[i];
  }
  __syncthreads();

  // ---- softmax over 64 scores (wave 0)
  if (w == 0) {
    const float scale = 0.036084391824351615f; // 1/sqrt(768)
    float v = sc[lane] * scale;
    float mx = v;
#pragma unroll
    for (int o = 32; o > 0; o >>= 1) mx = fmaxf(mx, __shfl_xor(mx, o, 64));
    float e = expf(v - mx);
    float sum = e;
#pragma unroll
    for (int o = 32; o > 0; o >>= 1) sum += __shfl_xor(sum, o, 64);
    sc[lane] = e / sum;
  }
  __syncthreads();

  // ---- pass 2: z[c] from LDS window. Threads 0..383, 2 cols each (u32).
  if (t < 384) {
    float a0 = 0.f, a1 = 0.f;
#pragma unroll 8
    for (int s = 0; s < SWIN; ++s) {
      float a = sc[s];
      unsigned pk = *(const unsigned*)&win[s][t * 2];
      float h0 = __bfloat162float(*(const __hip_bfloat16*)&pk);
      unsigned hi = pk >> 16;
      float h1 = __bfloat162float(*(const __hip_bfloat16*)&hi);
      a0 = fmaf(a, h0, a0);
      a1 = fmaf(a, h1, a1);
    }
    __hip_bfloat16 o[2];
    o[0] = __float2bfloat16(a0);
    o[1] = __float2bfloat16(a1);
    *(unsigned*)&zb[(size_t)g * EMB + t * 2] = *(const unsigned*)o;
  }
}

// ---------------------------------------------------------------------------
// res = Q + X ; out = LayerNorm(res) * g + b
// ---------------------------------------------------------------------------
__global__ __launch_bounds__(256)
void resid_ln_kernel(const float* __restrict__ Q, const float* __restrict__ X,
                     const float* __restrict__ gma, const float* __restrict__ bta,
                     float* __restrict__ out) {
  const int row = blockIdx.x;
  const int t = threadIdx.x;
  const int wave = t >> 6, lane = t & 63;
  __shared__ float red[4];

  float v[3];
  float s = 0.f;
#pragma unroll
  for (int r = 0; r < 3; ++r) {
    int c = t + r * 256;
    v[r] = Q[(size_t)row * EMB + c] + X[(size_t)row * EMB + c];
    s += v[r];
  }
#pragma unroll
  for (int o = 32; o > 0; o >>= 1) s += __shfl_xor(s, o, 64);
  if (lane == 0) red[wave] = s;
  __syncthreads();
  float mu = (red[0] + red[1] + red[2] + red[3]) * (1.f / EMB);
  __syncthreads();

  float q = 0.f;
#pragma unroll
  for (int r = 0; r < 3; ++r) {
    float d = v[r] - mu;
    q += d * d;
  }
#pragma unroll
  for (int o = 32; o > 0; o >>= 1) q += __shfl_xor(q, o, 64);
  if (lane == 0) red[wave] = q;
  __syncthreads();
  float var = (red[0] + red[1] + red[2] + red[3]) * (1.f / EMB);
  float inv = rsqrtf(var + 1e-5f);

#pragma unroll
  for (int r = 0; r < 3; ++r) {
    int c = t + r * 256;
    out[(size_t)row * EMB + c] = (v[r] - mu) * inv * gma[c] + bta[c];
  }
}

// ---------------------------------------------------------------------------
extern "C" void kernel_launch(void* const* d_in, const int* in_sizes, int n_in,
                              void* d_out, int out_size, void* d_ws, size_t ws_size,
                              hipStream_t stream) {
  const float* LR  = (const float*)d_in[0];
  const float* HR  = (const float*)d_in[1];
  const float* Wq  = (const float*)d_in[2];
  const float* bq  = (const float*)d_in[3];
  const float* Wk  = (const float*)d_in[4];
  // d_in[5] = Wk_b: softmax-invariant constant -> dropped (exact)
  const float* Wv  = (const float*)d_in[6];
  const float* bv  = (const float*)d_in[7];
  const float* Wo  = (const float*)d_in[8];
  const float* bo  = (const float*)d_in[9];
  const float* lng = (const float*)d_in[10];
  const float* lnb = (const float*)d_in[11];
  float* out = (float*)d_out;

  char* ws = (char*)d_ws;
  float* Qf = (float*)(ws + 0);                       // [1024][768] f32
  float* qt = (float*)(ws + 3145728);                 // [1024][768] f32
  float* x  = (float*)(ws + 6291456);                 // [1024][768] f32
  __hip_bfloat16* LRb  = (__hip_bfloat16*)(ws + 9437184);
  __hip_bfloat16* Qb   = (__hip_bfloat16*)(ws + 11010048);
  __hip_bfloat16* zb   = (__hip_bfloat16*)(ws + 12582912);
  __hip_bfloat16* yb   = (__hip_bfloat16*)(ws + 14155776);
  __hip_bfloat16* Wqb  = (__hip_bfloat16*)(ws + 15728640);
  __hip_bfloat16* WkTb = (__hip_bfloat16*)(ws + 16908288);
  __hip_bfloat16* Wvb  = (__hip_bfloat16*)(ws + 18087936);
  __hip_bfloat16* Wob  = (__hip_bfloat16*)(ws + 19267584);

  dim3 blk(256);
  dim3 gg(EMB / 64, NROWS / 64);                      // (12,16)

  // converts: LR, then 3 weights in one batched launch, then Wk transpose
  f2b_kernel<<<dim3(ROWF / 8 / 256), blk, 0, stream>>>(LR, LRb, ROWF / 8);
  f2b3_kernel<<<dim3(WELEM / 8 / 256, 3), blk, 0, stream>>>(
      Wq, Wqb, Wv, Wvb, Wo, Wob);
  f2bT_kernel<<<dim3(24, 24), blk, 0, stream>>>(Wk, WkTb);

  // Q = LR @ Wq^T + bq        (f32 for residual, bf16 for next GEMM)
  gemm_bf16<true, true, true><<<gg, blk, 0, stream>>>(
      LRb, Wqb, bq, Qf, Qb, NROWS, EMB, EMB);
  // qt = Q @ Wk               (Wk^T pre-transposed; f32 out for attn)
  gemm_bf16<false, true, false><<<gg, blk, 0, stream>>>(
      Qb, WkTb, nullptr, qt, nullptr, NROWS, EMB, EMB);
  // z = softmax(scale * qt . HR) @ HR   (bf16 out; HR read once from HBM)
  attn_kernel<<<dim3(NROWS), dim3(512), 0, stream>>>(HR, qt, zb);
  // y = z @ Wv^T + bv         (bf16 out)
  gemm_bf16<true, false, true><<<gg, blk, 0, stream>>>(
      zb, Wvb, bv, nullptr, yb, NROWS, EMB, EMB);
  // x = y @ Wo^T + bo         (f32 out)
  gemm_bf16<true, true, false><<<gg, blk, 0, stream>>>(
      yb, Wob, bo, x, nullptr, NROWS, EMB, EMB);
  // out = LN(Q + x) * g + b
  resid_ln_kernel<<<dim3(NROWS), blk, 0, stream>>>(Qf, x, lng, lnb, out);
}

// Round 4
// 92.207 us; speedup vs baseline: 2.5017x; 1.1079x over previous
//
#include <hip/hip_runtime.h>
#include <hip/hip_bf16.h>
#include <math.h>

#define EMB 768
#define NB 2
#define NWIN 512
#define NROWS (NB*NWIN)          // 1024
#define SWIN 64
#define HRDIM 32
#define ROWF (NROWS*EMB)         // 786432 elems in a [1024][768] buffer
#define WELEM (EMB*EMB)          // 589824

using bfrag = __attribute__((ext_vector_type(8))) short;   // 8 bf16 (4 VGPRs)
using f32x4 = __attribute__((ext_vector_type(4))) float;

#define GL16(g, l)  __builtin_amdgcn_global_load_lds(                         \
    (const __attribute__((address_space(1))) void*)(g),                       \
    (__attribute__((address_space(3))) void*)(l), 16, 0, 0)

// ---------------------------------------------------------------------------
// fp32 -> bf16 elementwise convert (8 elems/thread)
// ---------------------------------------------------------------------------
__global__ __launch_bounds__(256)
void f2b_kernel(const float* __restrict__ in, __hip_bfloat16* __restrict__ out,
                int n8) {
  int i = blockIdx.x * 256 + threadIdx.x;
  if (i >= n8) return;
  float4 a = *(const float4*)&in[(size_t)i * 8];
  float4 b = *(const float4*)&in[(size_t)i * 8 + 4];
  __hip_bfloat16 t[8];
  t[0] = __float2bfloat16(a.x); t[1] = __float2bfloat16(a.y);
  t[2] = __float2bfloat16(a.z); t[3] = __float2bfloat16(a.w);
  t[4] = __float2bfloat16(b.x); t[5] = __float2bfloat16(b.y);
  t[6] = __float2bfloat16(b.z); t[7] = __float2bfloat16(b.w);
  *(uint4*)&out[(size_t)i * 8] = *(const uint4*)t;
}

// batched variant: 3 weight matrices in one launch (blockIdx.y selects)
__global__ __launch_bounds__(256)
void f2b3_kernel(const float* __restrict__ inA, __hip_bfloat16* __restrict__ outA,
                 const float* __restrict__ inB, __hip_bfloat16* __restrict__ outB,
                 const float* __restrict__ inC, __hip_bfloat16* __restrict__ outC) {
  const float* in = (blockIdx.y == 0) ? inA : (blockIdx.y == 1) ? inB : inC;
  __hip_bfloat16* out = (blockIdx.y == 0) ? outA : (blockIdx.y == 1) ? outB : outC;
  int i = blockIdx.x * 256 + threadIdx.x;
  float4 a = *(const float4*)&in[(size_t)i * 8];
  float4 b = *(const float4*)&in[(size_t)i * 8 + 4];
  __hip_bfloat16 t[8];
  t[0] = __float2bfloat16(a.x); t[1] = __float2bfloat16(a.y);
  t[2] = __float2bfloat16(a.z); t[3] = __float2bfloat16(a.w);
  t[4] = __float2bfloat16(b.x); t[5] = __float2bfloat16(b.y);
  t[6] = __float2bfloat16(b.z); t[7] = __float2bfloat16(b.w);
  *(uint4*)&out[(size_t)i * 8] = *(const uint4*)t;
}

// ---------------------------------------------------------------------------
// fp32 [768][768] -> bf16 transposed: out[n][k] = in[k][n]
// ---------------------------------------------------------------------------
__global__ __launch_bounds__(256)
void f2bT_kernel(const float* __restrict__ in, __hip_bfloat16* __restrict__ out) {
  __shared__ float tile[32][33];
  const int bi = blockIdx.x, bj = blockIdx.y;
  const int c = threadIdx.x & 31, r8 = threadIdx.x >> 5;
#pragma unroll
  for (int rr = 0; rr < 4; ++rr) {
    int r = r8 + rr * 8;
    tile[c][r] = in[(size_t)(bi * 32 + r) * EMB + bj * 32 + c];
  }
  __syncthreads();
#pragma unroll
  for (int rr = 0; rr < 4; ++rr) {
    int n = r8 + rr * 8;
    out[(size_t)(bj * 32 + n) * EMB + bi * 32 + c] = __float2bfloat16(tile[n][c]);
  }
}

// ---------------------------------------------------------------------------
// MFMA bf16 GEMM: C[m][n] = sum_k A[m][k] * Bm[n][k]  (+ bias[n])
// 64x64 tile, BK=64, 4 waves. 3-deep LDS ring staged by global_load_lds(16B)
// with counted vmcnt (never 0 in steady state) + raw s_barrier: loads for
// tiles t+1,t+2 stay in flight across the barrier while tile t computes.
// K fixed at 768 (NT=12, fully unrolled so vmcnt literals are compile-time).
// XOR chunk swizzle via pre-swizzled global source (linear LDS dest).
// ---------------------------------------------------------------------------
template<bool BIAS, bool WF32, bool WB16>
__global__ __launch_bounds__(256)
void gemm_bf16(const __hip_bfloat16* __restrict__ A,
               const __hip_bfloat16* __restrict__ Bm,
               const float* __restrict__ bias,
               float* __restrict__ Cf, __hip_bfloat16* __restrict__ Cb,
               int M, int N) {
  constexpr int K = EMB;
  constexpr int NT = K / 64;          // 12
  __shared__ short lsA[3][64 * 64];   // 3 x 8 KB ring
  __shared__ short lsB[3][64 * 64];
  const int t = threadIdx.x;
  const int w = t >> 6, lane = t & 63;
  const int lr = lane & 15, lk = lane >> 4;
  const int m0 = blockIdx.y * 64, n0 = blockIdx.x * 64;

  const int r0 = t >> 3, c0 = t & 7;
  const int kc = c0 ^ (r0 & 7);
  const __hip_bfloat16* aptr0 = A + (size_t)(m0 + r0) * K + kc * 8;
  const __hip_bfloat16* aptr1 = A + (size_t)(m0 + r0 + 32) * K + kc * 8;
  const __hip_bfloat16* bptr0 = Bm + (size_t)(n0 + r0) * K + kc * 8;
  const __hip_bfloat16* bptr1 = Bm + (size_t)(n0 + r0 + 32) * K + kc * 8;
  const int wbase = w * 512;

  const int arow = w * 16 + lr;
  int aoff[2], boff[4][2];
#pragma unroll
  for (int ks = 0; ks < 2; ++ks)
    aoff[ks] = arow * 64 + (((ks << 2) | lk) ^ (arow & 7)) * 8;
#pragma unroll
  for (int f = 0; f < 4; ++f) {
    int br = f * 16 + lr;
#pragma unroll
    for (int ks = 0; ks < 2; ++ks)
      boff[f][ks] = br * 64 + (((ks << 2) | lk) ^ (br & 7)) * 8;
  }

  f32x4 acc[4];
#pragma unroll
  for (int f = 0; f < 4; ++f) acc[f] = (f32x4){0.f, 0.f, 0.f, 0.f};

  // prologue: stage tiles 0 and 1
#pragma unroll
  for (int p = 0; p < 2; ++p) {
    int ko = p * 64;
    GL16(aptr0 + ko, &lsA[p][wbase]);
    GL16(aptr1 + ko, &lsA[p][wbase + 2048]);
    GL16(bptr0 + ko, &lsB[p][wbase]);
    GL16(bptr1 + ko, &lsB[p][wbase + 2048]);
  }

#pragma unroll
  for (int kt = 0; kt < NT; ++kt) {
    // issue tile kt+2 into ring slot (kt+2)%3 (slot freed by the trailing
    // barrier of iteration kt-1)
    if (kt + 2 < NT) {
      constexpr int s3[NT + 2] = {0,1,2,0,1,2,0,1,2,0,1,2,0,1};
      const int sl = s3[kt + 2];
      int ko = (kt + 2) * 64;
      GL16(aptr0 + ko, &lsA[sl][wbase]);
      GL16(aptr1 + ko, &lsA[sl][wbase + 2048]);
      GL16(bptr0 + ko, &lsB[sl][wbase]);
      GL16(bptr1 + ko, &lsB[sl][wbase + 2048]);
    }
    // wait for OWN stages of tile kt only: 4 ops per in-flight tile remain
    if (kt + 2 < NT)      asm volatile("s_waitcnt vmcnt(8)" ::: "memory");
    else if (kt + 1 < NT) asm volatile("s_waitcnt vmcnt(4)" ::: "memory");
    else                  asm volatile("s_waitcnt vmcnt(0)" ::: "memory");
    __builtin_amdgcn_sched_barrier(0);
    __builtin_amdgcn_s_barrier();       // all waves: tile kt resident

    const int cur = kt % 3;
    bfrag a0 = *(const bfrag*)&lsA[cur][aoff[0]];
    bfrag a1 = *(const bfrag*)&lsA[cur][aoff[1]];
    bfrag b00 = *(const bfrag*)&lsB[cur][boff[0][0]];
    bfrag b01 = *(const bfrag*)&lsB[cur][boff[0][1]];
    bfrag b10 = *(const bfrag*)&lsB[cur][boff[1][0]];
    bfrag b11 = *(const bfrag*)&lsB[cur][boff[1][1]];
    bfrag b20 = *(const bfrag*)&lsB[cur][boff[2][0]];
    bfrag b21 = *(const bfrag*)&lsB[cur][boff[2][1]];
    bfrag b30 = *(const bfrag*)&lsB[cur][boff[3][0]];
    bfrag b31 = *(const bfrag*)&lsB[cur][boff[3][1]];
    acc[0] = __builtin_amdgcn_mfma_f32_16x16x32_bf16(a0, b00, acc[0], 0, 0, 0);
    acc[0] = __builtin_amdgcn_mfma_f32_16x16x32_bf16(a1, b01, acc[0], 0, 0, 0);
    acc[1] = __builtin_amdgcn_mfma_f32_16x16x32_bf16(a0, b10, acc[1], 0, 0, 0);
    acc[1] = __builtin_amdgcn_mfma_f32_16x16x32_bf16(a1, b11, acc[1], 0, 0, 0);
    acc[2] = __builtin_amdgcn_mfma_f32_16x16x32_bf16(a0, b20, acc[2], 0, 0, 0);
    acc[2] = __builtin_amdgcn_mfma_f32_16x16x32_bf16(a1, b21, acc[2], 0, 0, 0);
    acc[3] = __builtin_amdgcn_mfma_f32_16x16x32_bf16(a0, b30, acc[3], 0, 0, 0);
    acc[3] = __builtin_amdgcn_mfma_f32_16x16x32_bf16(a1, b31, acc[3], 0, 0, 0);

    // frag reads complete -> safe for any wave to overwrite slot cur next iter
    asm volatile("s_waitcnt lgkmcnt(0)" ::: "memory");
    __builtin_amdgcn_s_barrier();
    __builtin_amdgcn_sched_barrier(0);
  }

  float bs[4] = {0.f, 0.f, 0.f, 0.f};
  if (BIAS) {
#pragma unroll
    for (int f = 0; f < 4; ++f) bs[f] = bias[n0 + f * 16 + lr];
  }
#pragma unroll
  for (int f = 0; f < 4; ++f) {
    int n = n0 + f * 16 + lr;
#pragma unroll
    for (int j = 0; j < 4; ++j) {
      int m = m0 + w * 16 + lk * 4 + j;
      float v = acc[f][j] + bs[f];
      if (WF32) Cf[(size_t)m * N + n] = v;
      if (WB16) Cb[(size_t)m * N + n] = __float2bfloat16(v);
    }
  }
}

// ---------------------------------------------------------------------------
// Attention core, single HBM pass over HR.
// Pass 1: fp32 scores (full precision) + convert window to bf16 into LDS.
// Pass 2: weighted sum out of LDS. 512 threads, ~100 KB LDS -> 1 block/CU.
// ---------------------------------------------------------------------------
__global__ __launch_bounds__(512)
void attn_kernel(const float* __restrict__ HR, const float* __restrict__ qt,
                 __hip_bfloat16* __restrict__ zb) {
  const int g = blockIdx.x;
  const int b = g >> 9;
  const int n = g & 511;
  const int db = n >> 6, wb = (n >> 3) & 7, hb = n & 7;

  __shared__ float qs[EMB];
  __shared__ float sc[SWIN];
  __shared__ int   vb[SWIN];
  __shared__ short win[SWIN][EMB];   // 96 KB bf16 window cache

  const int t = threadIdx.x;
  const int w = t >> 6, lane = t & 63;

  if (t < 192)
    *(float4*)&qs[t * 4] = *(const float4*)&qt[(size_t)g * EMB + t * 4];
  if (t < SWIN) {
    int sd = t >> 4, sw = (t >> 2) & 3, sh = t & 3;
    int D = db * 4 + sd, W = wb * 4 + sw, H = hb * 4 + sh;
    vb[t] = (((b * HRDIM + D) * HRDIM + W) * HRDIM + H) * EMB;
  }
  __syncthreads();

  float4 qv[3];
#pragma unroll
  for (int r = 0; r < 3; ++r)
    qv[r] = *(const float4*)&qs[(lane + r * 64) * 4];

  float4 hv[8][3];
#pragma unroll
  for (int i = 0; i < 8; ++i) {
    const float* row = HR + vb[w * 8 + i];
#pragma unroll
    for (int r = 0; r < 3; ++r)
      hv[i][r] = *(const float4*)&row[(lane + r * 64) * 4];
  }

  float p[8];
#pragma unroll
  for (int i = 0; i < 8; ++i) {
    float acc = 0.f;
#pragma unroll
    for (int r = 0; r < 3; ++r) {
      acc = fmaf(hv[i][r].x, qv[r].x, acc);
      acc = fmaf(hv[i][r].y, qv[r].y, acc);
      acc = fmaf(hv[i][r].z, qv[r].z, acc);
      acc = fmaf(hv[i][r].w, qv[r].w, acc);
      __hip_bfloat16 o[4];
      o[0] = __float2bfloat16(hv[i][r].x);
      o[1] = __float2bfloat16(hv[i][r].y);
      o[2] = __float2bfloat16(hv[i][r].z);
      o[3] = __float2bfloat16(hv[i][r].w);
      *(uint2*)&win[w * 8 + i][(lane + r * 64) * 4] = *(const uint2*)o;
    }
    p[i] = acc;
  }
#pragma unroll
  for (int i = 0; i < 8; ++i) {
#pragma unroll
    for (int o = 32; o > 0; o >>= 1) p[i] += __shfl_xor(p[i], o, 64);
    if (lane == 0) sc[w * 8 + i] = p[i];
  }
  __syncthreads();

  if (w == 0) {
    const float scale = 0.036084391824351615f; // 1/sqrt(768)
    float v = sc[lane] * scale;
    float mx = v;
#pragma unroll
    for (int o = 32; o > 0; o >>= 1) mx = fmaxf(mx, __shfl_xor(mx, o, 64));
    float e = expf(v - mx);
    float sum = e;
#pragma unroll
    for (int o = 32; o > 0; o >>= 1) sum += __shfl_xor(sum, o, 64);
    sc[lane] = e / sum;
  }
  __syncthreads();

  if (t < 384) {
    float a0 = 0.f, a1 = 0.f;
#pragma unroll 8
    for (int s = 0; s < SWIN; ++s) {
      float a = sc[s];
      unsigned pk = *(const unsigned*)&win[s][t * 2];
      float h0 = __bfloat162float(*(const __hip_bfloat16*)&pk);
      unsigned hi = pk >> 16;
      float h1 = __bfloat162float(*(const __hip_bfloat16*)&hi);
      a0 = fmaf(a, h0, a0);
      a1 = fmaf(a, h1, a1);
    }
    __hip_bfloat16 o[2];
    o[0] = __float2bfloat16(a0);
    o[1] = __float2bfloat16(a1);
    *(unsigned*)&zb[(size_t)g * EMB + t * 2] = *(const unsigned*)o;
  }
}

// ---------------------------------------------------------------------------
// res = Q + X ; out = LayerNorm(res) * g + b
// ---------------------------------------------------------------------------
__global__ __launch_bounds__(256)
void resid_ln_kernel(const float* __restrict__ Q, const float* __restrict__ X,
                     const float* __restrict__ gma, const float* __restrict__ bta,
                     float* __restrict__ out) {
  const int row = blockIdx.x;
  const int t = threadIdx.x;
  const int wave = t >> 6, lane = t & 63;
  __shared__ float red[4];

  float v[3];
  float s = 0.f;
#pragma unroll
  for (int r = 0; r < 3; ++r) {
    int c = t + r * 256;
    v[r] = Q[(size_t)row * EMB + c] + X[(size_t)row * EMB + c];
    s += v[r];
  }
#pragma unroll
  for (int o = 32; o > 0; o >>= 1) s += __shfl_xor(s, o, 64);
  if (lane == 0) red[wave] = s;
  __syncthreads();
  float mu = (red[0] + red[1] + red[2] + red[3]) * (1.f / EMB);
  __syncthreads();

  float q = 0.f;
#pragma unroll
  for (int r = 0; r < 3; ++r) {
    float d = v[r] - mu;
    q += d * d;
  }
#pragma unroll
  for (int o = 32; o > 0; o >>= 1) q += __shfl_xor(q, o, 64);
  if (lane == 0) red[wave] = q;
  __syncthreads();
  float var = (red[0] + red[1] + red[2] + red[3]) * (1.f / EMB);
  float inv = rsqrtf(var + 1e-5f);

#pragma unroll
  for (int r = 0; r < 3; ++r) {
    int c = t + r * 256;
    out[(size_t)row * EMB + c] = (v[r] - mu) * inv * gma[c] + bta[c];
  }
}

// ---------------------------------------------------------------------------
extern "C" void kernel_launch(void* const* d_in, const int* in_sizes, int n_in,
                              void* d_out, int out_size, void* d_ws, size_t ws_size,
                              hipStream_t stream) {
  const float* LR  = (const float*)d_in[0];
  const float* HR  = (const float*)d_in[1];
  const float* Wq  = (const float*)d_in[2];
  const float* bq  = (const float*)d_in[3];
  const float* Wk  = (const float*)d_in[4];
  // d_in[5] = Wk_b: softmax-invariant constant -> dropped (exact)
  const float* Wv  = (const float*)d_in[6];
  const float* bv  = (const float*)d_in[7];
  const float* Wo  = (const float*)d_in[8];
  const float* bo  = (const float*)d_in[9];
  const float* lng = (const float*)d_in[10];
  const float* lnb = (const float*)d_in[11];
  float* out = (float*)d_out;

  char* ws = (char*)d_ws;
  float* Qf = (float*)(ws + 0);                       // [1024][768] f32
  float* qt = (float*)(ws + 3145728);                 // [1024][768] f32
  float* x  = (float*)(ws + 6291456);                 // [1024][768] f32
  __hip_bfloat16* LRb  = (__hip_bfloat16*)(ws + 9437184);
  __hip_bfloat16* Qb   = (__hip_bfloat16*)(ws + 11010048);
  __hip_bfloat16* zb   = (__hip_bfloat16*)(ws + 12582912);
  __hip_bfloat16* yb   = (__hip_bfloat16*)(ws + 14155776);
  __hip_bfloat16* Wqb  = (__hip_bfloat16*)(ws + 15728640);
  __hip_bfloat16* WkTb = (__hip_bfloat16*)(ws + 16908288);
  __hip_bfloat16* Wvb  = (__hip_bfloat16*)(ws + 18087936);
  __hip_bfloat16* Wob  = (__hip_bfloat16*)(ws + 19267584);

  dim3 blk(256);
  dim3 gg(EMB / 64, NROWS / 64);                      // (12,16)

  // converts: LR, then 3 weights in one batched launch, then Wk transpose
  f2b_kernel<<<dim3(ROWF / 8 / 256), blk, 0, stream>>>(LR, LRb, ROWF / 8);
  f2b3_kernel<<<dim3(WELEM / 8 / 256, 3), blk, 0, stream>>>(
      Wq, Wqb, Wv, Wvb, Wo, Wob);
  f2bT_kernel<<<dim3(24, 24), blk, 0, stream>>>(Wk, WkTb);

  // Q = LR @ Wq^T + bq        (f32 for residual, bf16 for next GEMM)
  gemm_bf16<true, true, true><<<gg, blk, 0, stream>>>(
      LRb, Wqb, bq, Qf, Qb, NROWS, EMB);
  // qt = Q @ Wk               (Wk^T pre-transposed; f32 out for attn)
  gemm_bf16<false, true, false><<<gg, blk, 0, stream>>>(
      Qb, WkTb, nullptr, qt, nullptr, NROWS, EMB);
  // z = softmax(scale * qt . HR) @ HR   (bf16 out; HR read once from HBM)
  attn_kernel<<<dim3(NROWS), dim3(512), 0, stream>>>(HR, qt, zb);
  // y = z @ Wv^T + bv         (bf16 out)
  gemm_bf16<true, false, true><<<gg, blk, 0, stream>>>(
      zb, Wvb, bv, nullptr, yb, NROWS, EMB);
  // x = y @ Wo^T + bo         (f32 out)
  gemm_bf16<true, true, false><<<gg, blk, 0, stream>>>(
      yb, Wob, bo, x, nullptr, NROWS, EMB);
  // out = LN(Q + x) * g + b
  resid_ln_kernel<<<dim3(NROWS), blk, 0, stream>>>(Qf, x, lng, lnb, out);
}